// Round 8
// baseline (256.139 us; speedup 1.0000x reference)
//
#include <hip/hip_runtime.h>
#include <math.h>

#ifndef M_PI
#define M_PI 3.14159265358979323846
#endif

// Problem constants (from the reference)
constexpr int    NSAMP  = 2048;
constexpr float  STEPf  = 2048.0f / 2047.0f;       // linspace(-1024,1024,2048) step
constexpr double STEPd  = 2048.0 / 2047.0;
constexpr float  DXf    = 6.0e-6f;                 // 3e-6 / 0.5
constexpr double DXd    = 6.0e-6;
constexpr float  EPSf   = 2.2204e-16f;
constexpr double EPSd   = 2.2204e-16;
constexpr double Kd     = 2.0 * M_PI / 3.55e-7;    // ~1.7698956e7
constexpr double INV2PI = 1.0 / (2.0 * M_PI);

// ---------------------------------------------------------------------------
// Gather per-(batch,particle) parameters.
// float prm, stride 16 per (b,p):
//   0:xm 1:ym
//   per set s in {hat,gt} at offset 2+6s:
//     +0: carg2    = carg^2          (y = x^2 = carg2*r2)
//     +1: crev     = carg/2pi
//     +2: c8       = 8/carg          (z = min(c8*invr, 1))
//     +3: csql     = (rs/2)*sqrt(0.636619772/carg)
//     +4: campcarg = (rs/2)*carg
//     +5: (unused)
// double dprm, stride 4 per (b,p): {xm, ym, cphrev_hat, cphrev_gt}
//   (cphrev = K/(2*zs*2pi), fp64, for the per-block phase tables)
// ---------------------------------------------------------------------------
__global__ void gather_params_kernel(const float* __restrict__ yh,
                                     const float* __restrict__ ygt,
                                     const int*   __restrict__ xs,
                                     const int*   __restrict__ ys,
                                     float* __restrict__ prm,
                                     double* __restrict__ dprm,
                                     double* __restrict__ acc) {
    int t = threadIdx.x;
    if (t == 0) *acc = 0.0;   // zero accumulator every launch (graph replay safe)
    if (t < 8) {
        const int M = 512;
        int b = t >> 2, p = t & 3;
        int ix = xs[b * 4 + p];
        int iy = ys[b * 4 + p];
        float rs_h = 50.0f  * yh [((b * 3 + 2) * M + iy) * M + ix];
        float zs_h = 200.0f * yh [((b * 3 + 1) * M + iy) * M + ix];
        float rs_g =          ygt[((b * 5 + 2) * M + iy) * M + ix];
        float zs_g =          ygt[((b * 5 + 1) * M + iy) * M + ix];
        double rph = (double)rs_h * 1e-6, zph = (double)zs_h * 1e-3;
        double rpg = (double)rs_g * 1e-6, zpg = (double)zs_g * 1e-3;

        double xm = ((double)(ix * 4) - 1024.0) * DXd;
        double ym = ((double)(iy * 4) - 1024.0) * DXd;

        float* o = prm + t * 16;
        o[0] = (float)xm;
        o[1] = (float)ym;

        double carg_h = Kd * rph / zph;
        o[2] = (float)(carg_h * carg_h);
        o[3] = (float)(carg_h * INV2PI);
        o[4] = (float)(8.0 / carg_h);
        o[5] = (float)(0.5 * rph * sqrt(0.636619772 / carg_h));
        o[6] = (float)(0.5 * rph * carg_h);
        o[7] = 0.0f;

        double carg_g = Kd * rpg / zpg;
        o[8]  = (float)(carg_g * carg_g);
        o[9]  = (float)(carg_g * INV2PI);
        o[10] = (float)(8.0 / carg_g);
        o[11] = (float)(0.5 * rpg * sqrt(0.636619772 / carg_g));
        o[12] = (float)(0.5 * rpg * carg_g);
        o[13] = 0.0f;
        o[14] = 0.0f; o[15] = 0.0f;

        double* d = dprm + t * 4;
        d[0] = xm;
        d[1] = ym;
        d[2] = Kd / (2.0 * zph) * INV2PI;
        d[3] = Kd / (2.0 * zpg) * INV2PI;
    }
}

// One particle-set J1*trig contribution. Branchless (round-6-proven): both J1
// branches computed on all lanes, clamped inputs keep everything finite,
// per-lane select. Phase sin/cos come from separable LDS tables via angle
// addition: sin(a+b) = sx*cy + cx*sy, cos(a+b) = cx*cy - sx*sy.
__device__ __forceinline__ void accum_set(float carg2, float crev, float c8,
                                          float csql, float campcarg,
                                          float rho, float invr, float r2,
                                          float ivs /* invr^1.5, shared */,
                                          float sx, float cx,
                                          const float* __restrict__ rt,
                                          float& S, float& C) {
    float y = carg2 * r2;                 // x^2: select predicate + poly var
    // --- large branch (always): truncated asymptotic, z clamped ---
    float z    = fminf(c8 * invr, 1.0f);
    float y2   = z * z;
    float rev1 = fmaf(crev, rho, -0.375f);        // (x - 3pi/4)/2pi
    float f1   = __builtin_amdgcn_fractf(rev1);
    float s1   = __builtin_amdgcn_sinf(f1);
    float c1   = __builtin_amdgcn_cosf(f1);
    float p1   = fmaf(y2, 0.183105e-2f, 1.0f);
    float p2   = fmaf(y2, -0.2002690873e-3f, 0.04687499995f);
    float a_l  = (csql * ivs) * fmaf(c1, p1, -(z * s1) * p2);
    // --- small branch (always): NR rational in y ---
    float yc  = fminf(y, 64.0f);
    float nt  = fmaf(yc, fmaf(yc, fmaf(yc, fmaf(yc, fmaf(yc,
                    -30.16036606f, 15704.48260f), -2972611.439f),
                    242396853.1f), -7895059235.0f), 72362614232.0f);
    float den = fmaf(yc, fmaf(yc, fmaf(yc, fmaf(yc, (yc + 376.9991397f),
                    99447.43394f), 18583304.74f), 2300535178.0f), 144725228442.0f);
    float a_s = (campcarg * nt) * __builtin_amdgcn_rcpf(den);
    // --- select on x^2 < 64 ---
    float amp = (y < 64.0f) ? a_s : a_l;
    // --- phase via separable tables (row entry is wave-uniform broadcast) ---
    float sy_ = rt[0], cy_ = rt[1];
    float s2 = fmaf(cx, sy_, sx * cy_);
    float c2 = fmaf(cx, cy_, -(sx * sy_));
    S = fmaf(amp, s2, S);
    C = fmaf(amp, c2, C);
}

// 4096 blocks x 256 threads. Block = 64(j) x 32(i) tile; thread = 1 column x
// 8 consecutive rows. Per-block fp64 phase tables in LDS (separable phase).
__global__ __launch_bounds__(256, 4) void holo_mse_kernel(
        const float* __restrict__ prm, const double* __restrict__ dprm,
        double* __restrict__ acc) {
    __shared__ float sp[128];
    __shared__ float colT[8][64][2];   // [set8][j_local][sin,cos]  4 KB
    __shared__ float rowT[8][32][2];   // [set8][i_local][sin,cos]  2 KB
    __shared__ float wsum[4];

    int blk  = blockIdx.x;
    int b    = blk >> 11;              // block-uniform batch
    int t2   = blk & 2047;
    int jblk = t2 & 31;                // 32 j-tiles of 64
    int iblk = t2 >> 5;                // 64 i-tiles of 32

    if (threadIdx.x < 128) sp[threadIdx.x] = prm[threadIdx.x];

    // Build phase tables: 512 col + 256 row entries; 3 per thread, uniform
    // branch per sweep (e<512 is uniform within each stride-256 pass).
    for (int e = threadIdx.x; e < 768; e += 256) {
        bool iscol = (e < 512);
        int  s8, coord, gidx;
        if (iscol) { s8 = e >> 6;          coord = e & 63; gidx = jblk * 64 + coord; }
        else       { int e2 = e - 512; s8 = e2 >> 5; coord = e2 & 31; gidx = iblk * 32 + coord; }
        int p = s8 >> 1, s = s8 & 1;
        double m  = dprm[b * 16 + p * 4 + (iscol ? 0 : 1)];
        double cr = dprm[b * 16 + p * 4 + 2 + s];
        double n  = ((double)gidx * STEPd - 1024.0) * DXd;
        double d  = n - m + EPSd;
        double a  = cr * d * d;
        a -= floor(a);
        float fr = (float)a;
        float sv = __builtin_amdgcn_sinf(fr);
        float cv = __builtin_amdgcn_cosf(fr);
        if (iscol) { colT[s8][coord][0] = sv; colT[s8][coord][1] = cv; }
        else       { rowT[s8][coord][0] = sv; rowT[s8][coord][1] = cv; }
    }
    __syncthreads();

    int jl = threadIdx.x & 63;         // column within tile (lane)
    int rg = threadIdx.x >> 6;         // row-group (wave id)
    int jg = jblk * 64 + jl;
    int i0 = iblk * 32 + rg * 8;

    float nj = fmaf((float)jg, STEPf, -1024.0f) * DXf;
    float ni[8];
    #pragma unroll
    for (int k = 0; k < 8; ++k)
        ni[k] = fmaf((float)(i0 + k), STEPf, -1024.0f) * DXf;

    float Sh[8], Ch[8], Sg[8], Cg[8];
    #pragma unroll
    for (int k = 0; k < 8; ++k) { Sh[k] = Ch[k] = Sg[k] = Cg[k] = 0.0f; }

    #pragma unroll
    for (int p = 0; p < 4; ++p) {
        const float* q = &sp[(b * 4 + p) * 16];
        float xm = q[0], ym = q[1];
        float carg2_h = q[2], crev_h = q[3], c8_h = q[4],
              csql_h  = q[5], cpc_h  = q[6];
        float carg2_g = q[8], crev_g = q[9], c8_g = q[10],
              csql_g  = q[11], cpc_g = q[12];
        float sxh = colT[p * 2 + 0][jl][0], cxh = colT[p * 2 + 0][jl][1];
        float sxg = colT[p * 2 + 1][jl][0], cxg = colT[p * 2 + 1][jl][1];
        float dx  = (nj - xm) + EPSf;
        float dx2 = dx * dx;
        #pragma unroll
        for (int k = 0; k < 8; ++k) {
            float dy   = (ni[k] - ym) + EPSf;
            float r2   = fmaf(dy, dy, dx2);
            float invr = __builtin_amdgcn_rsqf(r2);
            float rho  = r2 * invr;
            float ivs  = invr * __builtin_amdgcn_sqrtf(invr);  // invr^1.5
            accum_set(carg2_h, crev_h, c8_h, csql_h, cpc_h,
                      rho, invr, r2, ivs, sxh, cxh,
                      &rowT[p * 2 + 0][rg * 8 + k][0], Sh[k], Ch[k]);
            accum_set(carg2_g, crev_g, c8_g, csql_g, cpc_g,
                      rho, invr, r2, ivs, sxg, cxg,
                      &rowT[p * 2 + 1][rg * 8 + k][0], Sg[k], Cg[k]);
        }
    }

    float accd = 0.0f;
    #pragma unroll
    for (int k = 0; k < 8; ++k) {
        float reh = Sh[k] - 1.0f, reg = Sg[k] - 1.0f;
        float vh  = fmaf(reh, reh, Ch[k] * Ch[k]);
        float vg  = fmaf(reg, reg, Cg[k] * Cg[k]);
        float d   = vh - vg;
        accd = fmaf(d, d, accd);
    }

    #pragma unroll
    for (int off = 32; off > 0; off >>= 1) accd += __shfl_down(accd, off, 64);
    if ((threadIdx.x & 63) == 0) wsum[threadIdx.x >> 6] = accd;
    __syncthreads();
    if (threadIdx.x == 0) {
        float s = (wsum[0] + wsum[1]) + (wsum[2] + wsum[3]);
        atomicAdd(acc, (double)s);
    }
}

__global__ void finalize_kernel(const double* __restrict__ acc, float* __restrict__ out) {
    // mse * N^2 / 384^2 = sum / (B*N^2) * N^2/384^2 = sum / (2*384^2)
    out[0] = (float)(acc[0] / 294912.0);
}

extern "C" void kernel_launch(void* const* d_in, const int* in_sizes, int n_in,
                              void* d_out, int out_size, void* d_ws, size_t ws_size,
                              hipStream_t stream) {
    const float* yh  = (const float*)d_in[0];   // y_hat (2,3,512,512) f32
    const float* ygt = (const float*)d_in[1];   // y     (2,5,512,512) f32
    const int*   xs  = (const int*)d_in[2];     // (2,4) i32
    const int*   ys  = (const int*)d_in[3];     // (2,4) i32

    double* acc  = (double*)d_ws;
    float*  prm  = (float*)((char*)d_ws + 16);               // 128 floats
    double* dprm = (double*)((char*)d_ws + 16 + 512);        // 32 doubles
    float*  out  = (float*)d_out;

    gather_params_kernel<<<1, 128, 0, stream>>>(yh, ygt, xs, ys, prm, dprm, acc);
    holo_mse_kernel<<<4096, 256, 0, stream>>>(prm, dprm, acc);
    finalize_kernel<<<1, 1, 0, stream>>>(acc, out);
}

// Round 9
// 96.536 us; speedup vs baseline: 2.6533x; 2.6533x over previous
//
#include <hip/hip_runtime.h>
#include <math.h>

#ifndef M_PI
#define M_PI 3.14159265358979323846
#endif

// Problem constants (from the reference)
constexpr int    NSAMP  = 2048;
constexpr float  STEPf  = 2048.0f / 2047.0f;       // linspace(-1024,1024,2048) step
constexpr double STEPd  = 2048.0 / 2047.0;
constexpr float  DXf    = 6.0e-6f;                 // 3e-6 / 0.5
constexpr double DXd    = 6.0e-6;
constexpr float  EPSf   = 2.2204e-16f;
constexpr double Kd     = 2.0 * M_PI / 3.55e-7;    // ~1.7698956e7
constexpr double INV2PI = 1.0 / (2.0 * M_PI);
constexpr double TWOPI  = 2.0 * M_PI;

// ---------------------------------------------------------------------------
// Gather per-(batch,particle) parameters; fp64 precompute of per-set consts.
// prm layout per (b,p), stride 32:
//   0:xm 1:ym
//   per set s in {hat,gt} at offset 2+10s:
//     +0: carg2    = carg^2                   (y = x^2 = carg2*r2)
//     +1: crev     = carg/2pi
//     +2: c8       = 8/carg                   (z = min(c8*invr,1))
//     +3: csql     = (rs/2)*sqrt(0.636619772/carg)
//     +4: campcarg = (rs/2)*carg
//     +5: cph      = K/(2*zs*2pi)             (rev per m^2)
//     +6: cA       = 2*cph*DL                 (delta1 = cA*dy0 + cB, rev)
//     +7: cB       = cph*DL^2
//     +8: r2s      = sin(2pi*fract(2*cph*DL^2))   (constant rotor)
//     +9: r2c      = cos(2pi*fract(2*cph*DL^2))
//   (DL = 256*STEP*DX = row stride of a thread's consecutive points)
// ---------------------------------------------------------------------------
__global__ void gather_params_kernel(const float* __restrict__ yh,
                                     const float* __restrict__ ygt,
                                     const int*   __restrict__ xs,
                                     const int*   __restrict__ ys,
                                     float* __restrict__ prm,
                                     double* __restrict__ acc) {
    int t = threadIdx.x;
    if (t == 0) *acc = 0.0;   // zero accumulator every launch (graph replay safe)
    if (t < 8) {
        const int M = 512;
        int b = t >> 2, p = t & 3;
        int ix = xs[b * 4 + p];
        int iy = ys[b * 4 + p];
        float rs_h = 50.0f  * yh [((b * 3 + 2) * M + iy) * M + ix];
        float zs_h = 200.0f * yh [((b * 3 + 1) * M + iy) * M + ix];
        float rs_g =          ygt[((b * 5 + 2) * M + iy) * M + ix];
        float zs_g =          ygt[((b * 5 + 1) * M + iy) * M + ix];
        double rph = (double)rs_h * 1e-6, zph = (double)zs_h * 1e-3;
        double rpg = (double)rs_g * 1e-6, zpg = (double)zs_g * 1e-3;
        const double DL = 256.0 * STEPd * DXd;

        float* o = prm + t * 32;
        o[0] = (float)(((double)(ix * 4) - 1024.0) * DXd);
        o[1] = (float)(((double)(iy * 4) - 1024.0) * DXd);

        for (int s = 0; s < 2; ++s) {
            double rs = s ? rpg : rph;
            double zs = s ? zpg : zph;
            double carg = Kd * rs / zs;
            double cph  = Kd / (2.0 * zs) * INV2PI;
            double a2   = 2.0 * cph * DL * DL;
            a2 -= floor(a2);
            float* c = o + 2 + 10 * s;
            c[0] = (float)(carg * carg);
            c[1] = (float)(carg * INV2PI);
            c[2] = (float)(8.0 / carg);
            c[3] = (float)(0.5 * rs * sqrt(0.636619772 / carg));
            c[4] = (float)(0.5 * rs * carg);
            c[5] = (float)cph;
            c[6] = (float)(2.0 * cph * DL);
            c[7] = (float)(cph * DL * DL);
            c[8] = (float)sin(TWOPI * a2);
            c[9] = (float)cos(TWOPI * a2);
        }
        for (int e = 22; e < 32; ++e) o[e] = 0.0f;
    }
}

// J1 amplitude only (round-6-proven branchless form): both branches computed
// on all lanes, clamped inputs keep everything finite, per-lane select.
__device__ __forceinline__ float j1_amp(float carg2, float crev, float c8,
                                        float csql, float campcarg,
                                        float rho, float invr, float r2,
                                        float ivs /* invr^1.5, shared */) {
    float y = carg2 * r2;                 // x^2: select predicate + poly var
    // --- large branch: truncated asymptotic, z clamped ---
    float z    = fminf(c8 * invr, 1.0f);
    float y2   = z * z;
    float rev1 = fmaf(crev, rho, -0.375f);        // (x - 3pi/4)/2pi
    float f1   = __builtin_amdgcn_fractf(rev1);
    float s1   = __builtin_amdgcn_sinf(f1);
    float c1   = __builtin_amdgcn_cosf(f1);
    float p1   = fmaf(y2, 0.183105e-2f, 1.0f);
    float p2   = fmaf(y2, -0.2002690873e-3f, 0.04687499995f);
    float a_l  = (csql * ivs) * fmaf(c1, p1, -(z * s1) * p2);
    // --- small branch: NR rational in y, clamped ---
    float yc  = fminf(y, 64.0f);
    float nt  = fmaf(yc, fmaf(yc, fmaf(yc, fmaf(yc, fmaf(yc,
                    -30.16036606f, 15704.48260f), -2972611.439f),
                    242396853.1f), -7895059235.0f), 72362614232.0f);
    float den = fmaf(yc, fmaf(yc, fmaf(yc, fmaf(yc, (yc + 376.9991397f),
                    99447.43394f), 18583304.74f), 2300535178.0f), 144725228442.0f);
    float a_s = (campcarg * nt) * __builtin_amdgcn_rcpf(den);
    return (y < 64.0f) ? a_s : a_l;
}

// 4096 blocks x 256 threads; thread = (column j, rows i0+256k, k=0..7).
// Phase sin/cos via in-register 2nd-order rotation recurrence (4 trans per
// particle-set instead of 16).
__global__ __launch_bounds__(256, 3) void holo_mse_kernel(
        const float* __restrict__ prm, double* __restrict__ acc) {
    __shared__ float sp[256];
    __shared__ float wsum[4];
    sp[threadIdx.x] = prm[threadIdx.x];
    __syncthreads();

    int blk = blockIdx.x;
    int b   = blk >> 11;                            // block-uniform batch
    int r   = ((blk & 2047) << 8) + threadIdx.x;    // [0, 524288)
    int i0  = r >> 11;                              // row base (0..255)
    int j   = r & (NSAMP - 1);

    float nj = fmaf((float)j, STEPf, -1024.0f) * DXf;
    float ni[8];
    #pragma unroll
    for (int k = 0; k < 8; ++k)
        ni[k] = fmaf((float)(i0 + 256 * k), STEPf, -1024.0f) * DXf;

    float Sh[8], Ch[8], Sg[8], Cg[8];
    #pragma unroll
    for (int k = 0; k < 8; ++k) { Sh[k] = Ch[k] = Sg[k] = Cg[k] = 0.0f; }

    #pragma unroll
    for (int p = 0; p < 4; ++p) {
        const float* q = &sp[(b * 4 + p) * 32];
        float xm = q[0], ym = q[1];
        float dx  = (nj - xm) + EPSf;
        float dx2 = dx * dx;
        float dy0 = (ni[0] - ym) + EPSf;
        float r20 = fmaf(dy0, dy0, dx2);

        // --- rotor init, set hat: phi0 and delta1, then 2nd-order recurrence ---
        float sH, cH, sdH, cdH;
        {
            float cphv = q[7];
            float hi = cphv * r20;
            float er = fmaf(cphv, r20, -hi);
            float fr = __builtin_amdgcn_fractf(hi) + er;
            sH = __builtin_amdgcn_sinf(fr);
            cH = __builtin_amdgcn_cosf(fr);
            float d1 = fmaf(q[8], dy0, q[9]);
            float fd = __builtin_amdgcn_fractf(d1);
            sdH = __builtin_amdgcn_sinf(fd);
            cdH = __builtin_amdgcn_cosf(fd);
        }
        float r2sH = q[10], r2cH = q[11];
        // --- rotor init, set gt ---
        float sG, cG, sdG, cdG;
        {
            float cphv = q[17];
            float hi = cphv * r20;
            float er = fmaf(cphv, r20, -hi);
            float fr = __builtin_amdgcn_fractf(hi) + er;
            sG = __builtin_amdgcn_sinf(fr);
            cG = __builtin_amdgcn_cosf(fr);
            float d1 = fmaf(q[18], dy0, q[19]);
            float fd = __builtin_amdgcn_fractf(d1);
            sdG = __builtin_amdgcn_sinf(fd);
            cdG = __builtin_amdgcn_cosf(fd);
        }
        float r2sG = q[20], r2cG = q[21];

        #pragma unroll
        for (int k = 0; k < 8; ++k) {
            float dy   = (ni[k] - ym) + EPSf;
            float r2   = fmaf(dy, dy, dx2);
            float invr = __builtin_amdgcn_rsqf(r2);
            float rho  = r2 * invr;
            float ivs  = invr * __builtin_amdgcn_sqrtf(invr);  // invr^1.5
            float ampH = j1_amp(q[2], q[3], q[4], q[5], q[6], rho, invr, r2, ivs);
            Sh[k] = fmaf(ampH, sH, Sh[k]);
            Ch[k] = fmaf(ampH, cH, Ch[k]);
            float ampG = j1_amp(q[12], q[13], q[14], q[15], q[16], rho, invr, r2, ivs);
            Sg[k] = fmaf(ampG, sG, Sg[k]);
            Cg[k] = fmaf(ampG, cG, Cg[k]);
            if (k != 7) {   // compile-time under unroll: no runtime branch
                // rotate (s,c) by (sd,cd); then advance (sd,cd) by const rotor
                float sn = fmaf(sH, cdH, cH * sdH);
                float cn = fmaf(cH, cdH, -(sH * sdH));
                sH = sn; cH = cn;
                float sdn = fmaf(sdH, r2cH, cdH * r2sH);
                float cdn = fmaf(cdH, r2cH, -(sdH * r2sH));
                sdH = sdn; cdH = cdn;
                sn = fmaf(sG, cdG, cG * sdG);
                cn = fmaf(cG, cdG, -(sG * sdG));
                sG = sn; cG = cn;
                sdn = fmaf(sdG, r2cG, cdG * r2sG);
                cdn = fmaf(cdG, r2cG, -(sdG * r2sG));
                sdG = sdn; cdG = cdn;
            }
        }
    }

    float accd = 0.0f;
    #pragma unroll
    for (int k = 0; k < 8; ++k) {
        float reh = Sh[k] - 1.0f, reg = Sg[k] - 1.0f;
        float vh  = fmaf(reh, reh, Ch[k] * Ch[k]);
        float vg  = fmaf(reg, reg, Cg[k] * Cg[k]);
        float d   = vh - vg;
        accd = fmaf(d, d, accd);
    }

    #pragma unroll
    for (int off = 32; off > 0; off >>= 1) accd += __shfl_down(accd, off, 64);
    if ((threadIdx.x & 63) == 0) wsum[threadIdx.x >> 6] = accd;
    __syncthreads();
    if (threadIdx.x == 0) {
        float s = (wsum[0] + wsum[1]) + (wsum[2] + wsum[3]);
        atomicAdd(acc, (double)s);
    }
}

__global__ void finalize_kernel(const double* __restrict__ acc, float* __restrict__ out) {
    // mse * N^2 / 384^2 = sum / (B*N^2) * N^2/384^2 = sum / (2*384^2)
    out[0] = (float)(acc[0] / 294912.0);
}

extern "C" void kernel_launch(void* const* d_in, const int* in_sizes, int n_in,
                              void* d_out, int out_size, void* d_ws, size_t ws_size,
                              hipStream_t stream) {
    const float* yh  = (const float*)d_in[0];   // y_hat (2,3,512,512) f32
    const float* ygt = (const float*)d_in[1];   // y     (2,5,512,512) f32
    const int*   xs  = (const int*)d_in[2];     // (2,4) i32
    const int*   ys  = (const int*)d_in[3];     // (2,4) i32

    double* acc = (double*)d_ws;
    float*  prm = (float*)((char*)d_ws + 16);   // 256 floats
    float*  out = (float*)d_out;

    gather_params_kernel<<<1, 128, 0, stream>>>(yh, ygt, xs, ys, prm, acc);
    holo_mse_kernel<<<4096, 256, 0, stream>>>(prm, acc);
    finalize_kernel<<<1, 1, 0, stream>>>(acc, out);
}

// Round 10
// 95.647 us; speedup vs baseline: 2.6779x; 1.0093x over previous
//
#include <hip/hip_runtime.h>
#include <math.h>

#ifndef M_PI
#define M_PI 3.14159265358979323846
#endif

// Problem constants (from the reference)
constexpr int    NSAMP  = 2048;
constexpr float  STEPf  = 2048.0f / 2047.0f;       // linspace(-1024,1024,2048) step
constexpr double STEPd  = 2048.0 / 2047.0;
constexpr float  DXf    = 6.0e-6f;                 // 3e-6 / 0.5
constexpr double DXd    = 6.0e-6;
constexpr float  EPSf   = 2.2204e-16f;
constexpr double Kd     = 2.0 * M_PI / 3.55e-7;    // ~1.7698956e7
constexpr double INV2PI = 1.0 / (2.0 * M_PI);
constexpr double TWOPI  = 2.0 * M_PI;
constexpr float  DLf    = (float)(256.0 * STEPd * DXd);   // row stride (8 pts/thread)

// ---------------------------------------------------------------------------
// Gather per-(batch,particle) parameters; fp64 precompute of per-set consts.
// prm layout per (b,p), stride 32:
//   0:xm 1:ym
//   per set s in {hat,gt} at offset 2+10s:
//     +0: carg2    = carg^2                   (y = x^2 = carg2*r2)
//     +1: crev     = carg/2pi
//     +2: c8       = 8/carg                   (z = min(c8*invr,1))
//     +3: csql     = (rs/2)*sqrt(0.636619772/carg)
//     +4: campcarg = (rs/2)*carg
//     +5: cph      = K/(2*zs*2pi)             (rev per m^2)
//     +6: cA       = 2*cph*DL                 (delta1 = cA*dy0 + cB, rev)
//     +7: cB       = cph*DL^2
//     +8: r2s      = sin(2pi*fract(2*cph*DL^2))   (constant rotor)
//     +9: r2c      = cos(2pi*fract(2*cph*DL^2))
// ---------------------------------------------------------------------------
__global__ void gather_params_kernel(const float* __restrict__ yh,
                                     const float* __restrict__ ygt,
                                     const int*   __restrict__ xs,
                                     const int*   __restrict__ ys,
                                     float* __restrict__ prm,
                                     double* __restrict__ acc) {
    int t = threadIdx.x;
    if (t == 0) *acc = 0.0;   // zero accumulator every launch (graph replay safe)
    if (t < 8) {
        const int M = 512;
        int b = t >> 2, p = t & 3;
        int ix = xs[b * 4 + p];
        int iy = ys[b * 4 + p];
        float rs_h = 50.0f  * yh [((b * 3 + 2) * M + iy) * M + ix];
        float zs_h = 200.0f * yh [((b * 3 + 1) * M + iy) * M + ix];
        float rs_g =          ygt[((b * 5 + 2) * M + iy) * M + ix];
        float zs_g =          ygt[((b * 5 + 1) * M + iy) * M + ix];
        double rph = (double)rs_h * 1e-6, zph = (double)zs_h * 1e-3;
        double rpg = (double)rs_g * 1e-6, zpg = (double)zs_g * 1e-3;
        const double DL = 256.0 * STEPd * DXd;

        float* o = prm + t * 32;
        o[0] = (float)(((double)(ix * 4) - 1024.0) * DXd);
        o[1] = (float)(((double)(iy * 4) - 1024.0) * DXd);

        for (int s = 0; s < 2; ++s) {
            double rs = s ? rpg : rph;
            double zs = s ? zpg : zph;
            double carg = Kd * rs / zs;
            double cph  = Kd / (2.0 * zs) * INV2PI;
            double a2   = 2.0 * cph * DL * DL;
            a2 -= floor(a2);
            float* c = o + 2 + 10 * s;
            c[0] = (float)(carg * carg);
            c[1] = (float)(carg * INV2PI);
            c[2] = (float)(8.0 / carg);
            c[3] = (float)(0.5 * rs * sqrt(0.636619772 / carg));
            c[4] = (float)(0.5 * rs * carg);
            c[5] = (float)cph;
            c[6] = (float)(2.0 * cph * DL);
            c[7] = (float)(cph * DL * DL);
            c[8] = (float)sin(TWOPI * a2);
            c[9] = (float)cos(TWOPI * a2);
        }
        for (int e = 22; e < 32; ++e) o[e] = 0.0f;
    }
}

// J1 amplitude only (round-6-proven branchless form): both branches computed
// on all lanes, clamped inputs keep everything finite, per-lane select.
__device__ __forceinline__ float j1_amp(float carg2, float crev, float c8,
                                        float csql, float campcarg,
                                        float rho, float invr, float r2,
                                        float ivs /* invr^1.5, shared */) {
    float y = carg2 * r2;                 // x^2: select predicate + poly var
    // --- large branch: truncated asymptotic, z clamped ---
    float z    = fminf(c8 * invr, 1.0f);
    float y2   = z * z;
    float rev1 = fmaf(crev, rho, -0.375f);        // (x - 3pi/4)/2pi
    float f1   = __builtin_amdgcn_fractf(rev1);
    float s1   = __builtin_amdgcn_sinf(f1);
    float c1   = __builtin_amdgcn_cosf(f1);
    float p1   = fmaf(y2, 0.183105e-2f, 1.0f);
    float p2   = fmaf(y2, -0.2002690873e-3f, 0.04687499995f);
    float a_l  = (csql * ivs) * fmaf(c1, p1, -(z * s1) * p2);
    // --- small branch: NR rational in y, clamped ---
    float yc  = fminf(y, 64.0f);
    float nt  = fmaf(yc, fmaf(yc, fmaf(yc, fmaf(yc, fmaf(yc,
                    -30.16036606f, 15704.48260f), -2972611.439f),
                    242396853.1f), -7895059235.0f), 72362614232.0f);
    float den = fmaf(yc, fmaf(yc, fmaf(yc, fmaf(yc, (yc + 376.9991397f),
                    99447.43394f), 18583304.74f), 2300535178.0f), 144725228442.0f);
    float a_s = (campcarg * nt) * __builtin_amdgcn_rcpf(den);
    return (y < 64.0f) ? a_s : a_l;
}

// 4096 blocks x 256 threads; thread = (column j, rows i0+256k, k=0..7).
// All per-particle constants read via wave-uniform global loads -> SGPRs
// (no LDS staging, no VGPR pressure). Phase sin/cos via in-register rotor
// recurrence (4 trans per particle-set instead of 16).
__global__ __launch_bounds__(256, 4) void holo_mse_kernel(
        const float* __restrict__ prm, double* __restrict__ acc) {
    __shared__ float wsum[4];

    int blk = blockIdx.x;
    int b   = blk >> 11;                            // block-uniform batch
    int r   = ((blk & 2047) << 8) + threadIdx.x;    // [0, 524288)
    int i0  = r >> 11;                              // row base (0..255)
    int j   = r & (NSAMP - 1);

    float nj  = fmaf((float)j,  STEPf, -1024.0f) * DXf;
    float ni0 = fmaf((float)i0, STEPf, -1024.0f) * DXf;

    float Sh[8], Ch[8], Sg[8], Cg[8];
    #pragma unroll
    for (int k = 0; k < 8; ++k) { Sh[k] = Ch[k] = Sg[k] = Cg[k] = 0.0f; }

    #pragma unroll
    for (int p = 0; p < 4; ++p) {
        // uniform address (b uniform, p compile-time) -> scalar s_load to SGPRs
        const float* q = &prm[(b * 4 + p) * 32];
        float xm = q[0], ym = q[1];
        float dx  = (nj - xm) + EPSf;
        float dx2 = dx * dx;
        float dy0 = (ni0 - ym) + EPSf;
        float r20 = fmaf(dy0, dy0, dx2);

        // --- rotor init, set hat: phi0 and delta1 ---
        float sH, cH, sdH, cdH;
        {
            float cphv = q[7];
            float hi = cphv * r20;
            float er = fmaf(cphv, r20, -hi);
            float fr = __builtin_amdgcn_fractf(hi) + er;
            sH = __builtin_amdgcn_sinf(fr);
            cH = __builtin_amdgcn_cosf(fr);
            float d1 = fmaf(q[8], dy0, q[9]);
            float fd = __builtin_amdgcn_fractf(d1);
            sdH = __builtin_amdgcn_sinf(fd);
            cdH = __builtin_amdgcn_cosf(fd);
        }
        // --- rotor init, set gt ---
        float sG, cG, sdG, cdG;
        {
            float cphv = q[17];
            float hi = cphv * r20;
            float er = fmaf(cphv, r20, -hi);
            float fr = __builtin_amdgcn_fractf(hi) + er;
            sG = __builtin_amdgcn_sinf(fr);
            cG = __builtin_amdgcn_cosf(fr);
            float d1 = fmaf(q[18], dy0, q[19]);
            float fd = __builtin_amdgcn_fractf(d1);
            sdG = __builtin_amdgcn_sinf(fd);
            cdG = __builtin_amdgcn_cosf(fd);
        }

        #pragma unroll
        for (int k = 0; k < 8; ++k) {
            float dy   = fmaf((float)k, DLf, dy0);   // = (ni_k - ym) + EPS
            float r2   = fmaf(dy, dy, dx2);
            float invr = __builtin_amdgcn_rsqf(r2);
            float rho  = r2 * invr;
            float ivs  = invr * __builtin_amdgcn_sqrtf(invr);  // invr^1.5
            float ampH = j1_amp(q[2], q[3], q[4], q[5], q[6], rho, invr, r2, ivs);
            Sh[k] = fmaf(ampH, sH, Sh[k]);
            Ch[k] = fmaf(ampH, cH, Ch[k]);
            float ampG = j1_amp(q[12], q[13], q[14], q[15], q[16], rho, invr, r2, ivs);
            Sg[k] = fmaf(ampG, sG, Sg[k]);
            Cg[k] = fmaf(ampG, cG, Cg[k]);
            if (k != 7) {   // compile-time under unroll: no runtime branch
                // rotate (s,c) by (sd,cd); advance (sd,cd) by const rotor
                float sn = fmaf(sH, cdH, cH * sdH);
                float cn = fmaf(cH, cdH, -(sH * sdH));
                sH = sn; cH = cn;
                float sdn = fmaf(sdH, q[11], cdH * q[10]);
                float cdn = fmaf(cdH, q[11], -(sdH * q[10]));
                sdH = sdn; cdH = cdn;
                sn = fmaf(sG, cdG, cG * sdG);
                cn = fmaf(cG, cdG, -(sG * sdG));
                sG = sn; cG = cn;
                sdn = fmaf(sdG, q[21], cdG * q[20]);
                cdn = fmaf(cdG, q[21], -(sdG * q[20]));
                sdG = sdn; cdG = cdn;
            }
        }
    }

    float accd = 0.0f;
    #pragma unroll
    for (int k = 0; k < 8; ++k) {
        float reh = Sh[k] - 1.0f, reg = Sg[k] - 1.0f;
        float vh  = fmaf(reh, reh, Ch[k] * Ch[k]);
        float vg  = fmaf(reg, reg, Cg[k] * Cg[k]);
        float d   = vh - vg;
        accd = fmaf(d, d, accd);
    }

    #pragma unroll
    for (int off = 32; off > 0; off >>= 1) accd += __shfl_down(accd, off, 64);
    if ((threadIdx.x & 63) == 0) wsum[threadIdx.x >> 6] = accd;
    __syncthreads();
    if (threadIdx.x == 0) {
        float s = (wsum[0] + wsum[1]) + (wsum[2] + wsum[3]);
        atomicAdd(acc, (double)s);
    }
}

__global__ void finalize_kernel(const double* __restrict__ acc, float* __restrict__ out) {
    // mse * N^2 / 384^2 = sum / (B*N^2) * N^2/384^2 = sum / (2*384^2)
    out[0] = (float)(acc[0] / 294912.0);
}

extern "C" void kernel_launch(void* const* d_in, const int* in_sizes, int n_in,
                              void* d_out, int out_size, void* d_ws, size_t ws_size,
                              hipStream_t stream) {
    const float* yh  = (const float*)d_in[0];   // y_hat (2,3,512,512) f32
    const float* ygt = (const float*)d_in[1];   // y     (2,5,512,512) f32
    const int*   xs  = (const int*)d_in[2];     // (2,4) i32
    const int*   ys  = (const int*)d_in[3];     // (2,4) i32

    double* acc = (double*)d_ws;
    float*  prm = (float*)((char*)d_ws + 16);   // 256 floats
    float*  out = (float*)d_out;

    gather_params_kernel<<<1, 128, 0, stream>>>(yh, ygt, xs, ys, prm, acc);
    holo_mse_kernel<<<4096, 256, 0, stream>>>(prm, acc);
    finalize_kernel<<<1, 1, 0, stream>>>(acc, out);
}

// Round 11
// 82.650 us; speedup vs baseline: 3.0991x; 1.1573x over previous
//
#include <hip/hip_runtime.h>
#include <math.h>

#ifndef M_PI
#define M_PI 3.14159265358979323846
#endif

// Problem constants (from the reference)
constexpr int    NSAMP  = 2048;
constexpr float  STEPf  = 2048.0f / 2047.0f;       // linspace(-1024,1024,2048) step
constexpr double STEPd  = 2048.0 / 2047.0;
constexpr float  DXf    = 6.0e-6f;                 // 3e-6 / 0.5
constexpr double DXd    = 6.0e-6;
constexpr float  EPSf   = 2.2204e-16f;
constexpr double Kd     = 2.0 * M_PI / 3.55e-7;    // ~1.7698956e7
constexpr double INV2PI = 1.0 / (2.0 * M_PI);
constexpr double TWOPI  = 2.0 * M_PI;
// Row stride of a thread's 8 consecutive points (contiguous-tile mapping)
constexpr float  DLROW  = (float)(STEPd * DXd);

// ---------------------------------------------------------------------------
// Gather per-(batch,particle) parameters; fp64 precompute of per-set consts.
// prm layout per (b,p), stride 32:
//   0:xm 1:ym
//   per set s in {hat,gt} at offset 2+10s:
//     +0: carg2    = carg^2                   (y = x^2 = carg2*r2)
//     +1: crev     = carg/2pi
//     +2: c8       = 8/carg                   (z = c8*invr)
//     +3: csql     = (rs/2)*sqrt(0.636619772/carg)
//     +4: campcarg = (rs/2)*carg
//     +5: cph      = K/(2*zs*2pi)             (rev per m^2)
//     +6: cA       = 2*cph*DL                 (delta1 = cA*dy0 + cB, rev)
//     +7: cB       = cph*DL^2
//     +8: r2s      = sin(2pi*fract(2*cph*DL^2))   (constant rotor)
//     +9: r2c      = cos(2pi*fract(2*cph*DL^2))
//   DL = STEP*DX (adjacent rows).
// ---------------------------------------------------------------------------
__global__ void gather_params_kernel(const float* __restrict__ yh,
                                     const float* __restrict__ ygt,
                                     const int*   __restrict__ xs,
                                     const int*   __restrict__ ys,
                                     float* __restrict__ prm,
                                     double* __restrict__ acc) {
    int t = threadIdx.x;
    if (t == 0) *acc = 0.0;   // zero accumulator every launch (graph replay safe)
    if (t < 8) {
        const int M = 512;
        int b = t >> 2, p = t & 3;
        int ix = xs[b * 4 + p];
        int iy = ys[b * 4 + p];
        float rs_h = 50.0f  * yh [((b * 3 + 2) * M + iy) * M + ix];
        float zs_h = 200.0f * yh [((b * 3 + 1) * M + iy) * M + ix];
        float rs_g =          ygt[((b * 5 + 2) * M + iy) * M + ix];
        float zs_g =          ygt[((b * 5 + 1) * M + iy) * M + ix];
        double rph = (double)rs_h * 1e-6, zph = (double)zs_h * 1e-3;
        double rpg = (double)rs_g * 1e-6, zpg = (double)zs_g * 1e-3;
        const double DL = STEPd * DXd;

        float* o = prm + t * 32;
        o[0] = (float)(((double)(ix * 4) - 1024.0) * DXd);
        o[1] = (float)(((double)(iy * 4) - 1024.0) * DXd);

        for (int s = 0; s < 2; ++s) {
            double rs = s ? rpg : rph;
            double zs = s ? zpg : zph;
            double carg = Kd * rs / zs;
            double cph  = Kd / (2.0 * zs) * INV2PI;
            double a2   = 2.0 * cph * DL * DL;
            a2 -= floor(a2);
            float* c = o + 2 + 10 * s;
            c[0] = (float)(carg * carg);
            c[1] = (float)(carg * INV2PI);
            c[2] = (float)(8.0 / carg);
            c[3] = (float)(0.5 * rs * sqrt(0.636619772 / carg));
            c[4] = (float)(0.5 * rs * carg);
            c[5] = (float)cph;
            c[6] = (float)(2.0 * cph * DL);
            c[7] = (float)(cph * DL * DL);
            c[8] = (float)sin(TWOPI * a2);
            c[9] = (float)cos(TWOPI * a2);
        }
        for (int e = 22; e < 32; ++e) o[e] = 0.0f;
    }
}

// Full J1 amplitude (round-6-proven branchless form): both branches computed,
// clamped inputs keep all lanes finite, per-lane select.
__device__ __forceinline__ float j1_amp_full(float carg2, float crev, float c8,
                                             float csql, float campcarg,
                                             float rho, float invr, float r2,
                                             float ivs /* invr^1.5 */) {
    float y = carg2 * r2;
    float z    = fminf(c8 * invr, 1.0f);
    float y2   = z * z;
    float rev1 = fmaf(crev, rho, -0.375f);
    float f1   = __builtin_amdgcn_fractf(rev1);
    float s1   = __builtin_amdgcn_sinf(f1);
    float c1   = __builtin_amdgcn_cosf(f1);
    float p1   = fmaf(y2, 0.183105e-2f, 1.0f);
    float p2   = fmaf(y2, -0.2002690873e-3f, 0.04687499995f);
    float a_l  = (csql * ivs) * fmaf(c1, p1, -(z * s1) * p2);
    float yc  = fminf(y, 64.0f);
    float nt  = fmaf(yc, fmaf(yc, fmaf(yc, fmaf(yc, fmaf(yc,
                    -30.16036606f, 15704.48260f), -2972611.439f),
                    242396853.1f), -7895059235.0f), 72362614232.0f);
    float den = fmaf(yc, fmaf(yc, fmaf(yc, fmaf(yc, (yc + 376.9991397f),
                    99447.43394f), 18583304.74f), 2300535178.0f), 144725228442.0f);
    float a_s = (campcarg * nt) * __builtin_amdgcn_rcpf(den);
    return (y < 64.0f) ? a_s : a_l;
}

// Asymptotic-only amplitude: valid when the whole tile is outside the x<8
// disc (block-uniform guarantee y>=64 -> z<=1, no clamps/selects needed).
__device__ __forceinline__ float j1_amp_large(float crev, float c8, float csql,
                                              float rho, float invr,
                                              float ivs /* invr^1.5 */) {
    float z    = c8 * invr;
    float y2   = z * z;
    float rev1 = fmaf(crev, rho, -0.375f);
    float f1   = __builtin_amdgcn_fractf(rev1);
    float s1   = __builtin_amdgcn_sinf(f1);
    float c1   = __builtin_amdgcn_cosf(f1);
    float p1   = fmaf(y2, 0.183105e-2f, 1.0f);
    float p2   = fmaf(y2, -0.2002690873e-3f, 0.04687499995f);
    return (csql * ivs) * fmaf(c1, p1, -(z * s1) * p2);
}

// The 4-particle x 8-row accumulation loop; FULL selects the J1 evaluator.
// Rotor recurrence gives phase sin/cos with 4 trans per particle-set.
template <bool FULL>
__device__ __forceinline__ void particle_loop(const float* __restrict__ qb,
                                              float nj, float ni0,
                                              float (&Sh)[8], float (&Ch)[8],
                                              float (&Sg)[8], float (&Cg)[8]) {
    #pragma unroll
    for (int p = 0; p < 4; ++p) {
        const float* q = qb + p * 32;   // uniform address -> SGPR s_load
        float xm = q[0], ym = q[1];
        float dx  = (nj - xm) + EPSf;
        float dx2 = dx * dx;
        float dy0 = (ni0 - ym) + EPSf;
        float r20 = fmaf(dy0, dy0, dx2);

        float sH, cH, sdH, cdH;
        {
            float cphv = q[7];
            float hi = cphv * r20;
            float er = fmaf(cphv, r20, -hi);
            float fr = __builtin_amdgcn_fractf(hi) + er;
            sH = __builtin_amdgcn_sinf(fr);
            cH = __builtin_amdgcn_cosf(fr);
            float d1 = fmaf(q[8], dy0, q[9]);
            float fd = __builtin_amdgcn_fractf(d1);
            sdH = __builtin_amdgcn_sinf(fd);
            cdH = __builtin_amdgcn_cosf(fd);
        }
        float sG, cG, sdG, cdG;
        {
            float cphv = q[17];
            float hi = cphv * r20;
            float er = fmaf(cphv, r20, -hi);
            float fr = __builtin_amdgcn_fractf(hi) + er;
            sG = __builtin_amdgcn_sinf(fr);
            cG = __builtin_amdgcn_cosf(fr);
            float d1 = fmaf(q[18], dy0, q[19]);
            float fd = __builtin_amdgcn_fractf(d1);
            sdG = __builtin_amdgcn_sinf(fd);
            cdG = __builtin_amdgcn_cosf(fd);
        }

        #pragma unroll
        for (int k = 0; k < 8; ++k) {
            float dy   = fmaf((float)k, DLROW, dy0);
            float r2   = fmaf(dy, dy, dx2);
            float invr = __builtin_amdgcn_rsqf(r2);
            float rho  = r2 * invr;
            float ivs  = invr * __builtin_amdgcn_sqrtf(invr);
            float ampH, ampG;
            if constexpr (FULL) {
                ampH = j1_amp_full(q[2], q[3], q[4], q[5], q[6], rho, invr, r2, ivs);
                ampG = j1_amp_full(q[12], q[13], q[14], q[15], q[16], rho, invr, r2, ivs);
            } else {
                ampH = j1_amp_large(q[3], q[4], q[5], rho, invr, ivs);
                ampG = j1_amp_large(q[13], q[14], q[15], rho, invr, ivs);
            }
            Sh[k] = fmaf(ampH, sH, Sh[k]);
            Ch[k] = fmaf(ampH, cH, Ch[k]);
            Sg[k] = fmaf(ampG, sG, Sg[k]);
            Cg[k] = fmaf(ampG, cG, Cg[k]);
            if (k != 7) {   // compile-time under unroll
                float sn = fmaf(sH, cdH, cH * sdH);
                float cn = fmaf(cH, cdH, -(sH * sdH));
                sH = sn; cH = cn;
                float sdn = fmaf(sdH, q[11], cdH * q[10]);
                float cdn = fmaf(cdH, q[11], -(sdH * q[10]));
                sdH = sdn; cdH = cdn;
                sn = fmaf(sG, cdG, cG * sdG);
                cn = fmaf(cG, cdG, -(sG * sdG));
                sG = sn; cG = cn;
                sdn = fmaf(sdG, q[21], cdG * q[20]);
                cdn = fmaf(cdG, q[21], -(sdG * q[20]));
                sdG = sdn; cdG = cdn;
            }
        }
    }
}

// 4096 blocks x 256 threads. Block = contiguous 64(j) x 32(i) tile; thread =
// 1 column x 8 consecutive rows. Block-uniform disc test picks fast
// (asymptotic-only) or full body — one uniform branch, two straight-line
// unrolled bodies, no in-loop control flow.
__global__ __launch_bounds__(256, 4) void holo_mse_kernel(
        const float* __restrict__ prm, double* __restrict__ acc) {
    __shared__ float wsum[4];

    int blk  = blockIdx.x;
    int b    = blk >> 11;              // block-uniform batch
    int t2   = blk & 2047;
    int jblk = t2 & 31;                // 32 j-tiles of 64
    int iblk = t2 >> 5;                // 64 i-tiles of 32
    int jl   = threadIdx.x & 63;
    int rg   = threadIdx.x >> 6;
    int j    = jblk * 64 + jl;
    int i0   = iblk * 32 + rg * 8;

    float nj  = fmaf((float)j,  STEPf, -1024.0f) * DXf;
    float ni0 = fmaf((float)i0, STEPf, -1024.0f) * DXf;

    // tile bounds (block-uniform)
    float tx0 = fmaf((float)(jblk * 64),      STEPf, -1024.0f) * DXf;
    float tx1 = fmaf((float)(jblk * 64 + 63), STEPf, -1024.0f) * DXf;
    float ty0 = fmaf((float)(iblk * 32),      STEPf, -1024.0f) * DXf;
    float ty1 = fmaf((float)(iblk * 32 + 31), STEPf, -1024.0f) * DXf;

    const float* qb = &prm[b * 4 * 32];
    bool anySmall = false;
    #pragma unroll
    for (int p = 0; p < 4; ++p) {
        const float* q = qb + p * 32;
        float xm = q[0], ym = q[1];
        float nx = fminf(fmaxf(xm, tx0), tx1);
        float ny = fminf(fmaxf(ym, ty0), ty1);
        float ddx = nx - xm, ddy = ny - ym;
        float d2 = fmaf(ddx, ddx, ddy * ddy);
        // threshold 66 (not 64): slack covers fp rounding + EPS perturbation
        anySmall = anySmall || (q[2] * d2 < 66.0f) || (q[12] * d2 < 66.0f);
    }

    float Sh[8], Ch[8], Sg[8], Cg[8];
    #pragma unroll
    for (int k = 0; k < 8; ++k) { Sh[k] = Ch[k] = Sg[k] = Cg[k] = 0.0f; }

    if (anySmall) particle_loop<true >(qb, nj, ni0, Sh, Ch, Sg, Cg);
    else          particle_loop<false>(qb, nj, ni0, Sh, Ch, Sg, Cg);

    float accd = 0.0f;
    #pragma unroll
    for (int k = 0; k < 8; ++k) {
        float reh = Sh[k] - 1.0f, reg = Sg[k] - 1.0f;
        float vh  = fmaf(reh, reh, Ch[k] * Ch[k]);
        float vg  = fmaf(reg, reg, Cg[k] * Cg[k]);
        float d   = vh - vg;
        accd = fmaf(d, d, accd);
    }

    #pragma unroll
    for (int off = 32; off > 0; off >>= 1) accd += __shfl_down(accd, off, 64);
    if ((threadIdx.x & 63) == 0) wsum[threadIdx.x >> 6] = accd;
    __syncthreads();
    if (threadIdx.x == 0) {
        float s = (wsum[0] + wsum[1]) + (wsum[2] + wsum[3]);
        atomicAdd(acc, (double)s);
    }
}

__global__ void finalize_kernel(const double* __restrict__ acc, float* __restrict__ out) {
    // mse * N^2 / 384^2 = sum / (B*N^2) * N^2/384^2 = sum / (2*384^2)
    out[0] = (float)(acc[0] / 294912.0);
}

extern "C" void kernel_launch(void* const* d_in, const int* in_sizes, int n_in,
                              void* d_out, int out_size, void* d_ws, size_t ws_size,
                              hipStream_t stream) {
    const float* yh  = (const float*)d_in[0];   // y_hat (2,3,512,512) f32
    const float* ygt = (const float*)d_in[1];   // y     (2,5,512,512) f32
    const int*   xs  = (const int*)d_in[2];     // (2,4) i32
    const int*   ys  = (const int*)d_in[3];     // (2,4) i32

    double* acc = (double*)d_ws;
    float*  prm = (float*)((char*)d_ws + 16);   // 256 floats
    float*  out = (float*)d_out;

    gather_params_kernel<<<1, 128, 0, stream>>>(yh, ygt, xs, ys, prm, acc);
    holo_mse_kernel<<<4096, 256, 0, stream>>>(prm, acc);
    finalize_kernel<<<1, 1, 0, stream>>>(acc, out);
}